// Round 1
// baseline (1766.543 us; speedup 1.0000x reference)
//
#include <hip/hip_runtime.h>

#define HH 128
static constexpr int kN0 = 100000;
static constexpr int kC1 = 10000;
static constexpr int kC2 = 1000;

// ---------------- CSR build ----------------

__global__ void hist_kernel(const int* __restrict__ key, int n, int* __restrict__ counts) {
  int g = blockIdx.x * 256 + threadIdx.x;
  if (g < n) atomicAdd(&counts[key[g]], 1);
}

__global__ void degw_kernel(const int* __restrict__ col, const float* __restrict__ ew, int n,
                            float* __restrict__ deg) {
  int g = blockIdx.x * 256 + threadIdx.x;
  if (g < n) atomicAdd(&deg[col[g]], ew[g]);
}

// 5 independent exclusive scans, one block each (block = 1024 threads).
__global__ __launch_bounds__(1024) void scan5_kernel(
    const int* __restrict__ c0, int* __restrict__ s0, int n0,
    const int* __restrict__ c1, int* __restrict__ s1, int n1,
    const int* __restrict__ c2, int* __restrict__ s2, int n2,
    const int* __restrict__ c3, int* __restrict__ s3, int n3,
    const int* __restrict__ c4, int* __restrict__ s4, int n4) {
  const int* c; int* s; int n;
  switch (blockIdx.x) {
    case 0: c = c0; s = s0; n = n0; break;
    case 1: c = c1; s = s1; n = n1; break;
    case 2: c = c2; s = s2; n = n2; break;
    case 3: c = c3; s = s3; n = n3; break;
    default: c = c4; s = s4; n = n4; break;
  }
  __shared__ int sh[1024];
  int t = threadIdx.x;
  int chunk = (n + 1023) >> 10;
  int b = t * chunk;
  int e = b + chunk; if (e > n) e = n;
  int sum = 0;
  for (int i = b; i < e; i++) sum += c[i];
  sh[t] = sum;
  __syncthreads();
  for (int o = 1; o < 1024; o <<= 1) {
    int v = (t >= o) ? sh[t - o] : 0;
    __syncthreads();
    sh[t] += v;
    __syncthreads();
  }
  int run = sh[t] - sum;  // exclusive prefix of this thread's chunk
  for (int i = b; i < e; i++) { s[i] = run; run += c[i]; }
  if (b < n && e == n) s[n] = run;
}

__global__ void scatter_kernel(const int* __restrict__ key, int n,
                               const int* __restrict__ starts, int* __restrict__ cursor,
                               int* __restrict__ idx) {
  int g = blockIdx.x * 256 + threadIdx.x;
  if (g < n) {
    int k = key[g];
    int p = atomicAdd(&cursor[k], 1);
    idx[starts[k] + p] = g;
  }
}

__global__ void dinv_kernel(const int* __restrict__ cnt0, float* __restrict__ d0,
                            const int* __restrict__ cnt1, float* __restrict__ d1o,
                            const float* __restrict__ deg1, float* __restrict__ d1w,
                            const float* __restrict__ deg2, float* __restrict__ d2) {
  int g = blockIdx.x * 256 + threadIdx.x;
  if (g < kN0) { int c = cnt0[g]; d0[g] = c > 0 ? rsqrtf((float)c) : 0.f; }
  if (g < kC1) {
    int c = cnt1[g]; d1o[g] = c > 0 ? rsqrtf((float)c) : 0.f;
    float w = deg1[g]; d1w[g] = w > 0.f ? rsqrtf(w) : 0.f;
  }
  if (g < kC2) { float w = deg2[g]; d2[g] = w > 0.f ? rsqrtf(w) : 0.f; }
}

// ---------------- GEMM: Y[N x 128] = X[N x 128] @ W[128 x 128] (+bias) ----------------
// Block: 256 threads, 32 rows. Thread tile 4 rows x 4 cols. W staged in two 64-k halves
// (32 KB) + X tile 16 KB => 48 KB LDS, 3 blocks/CU.
__global__ __launch_bounds__(256) void matmul_kernel(const float* __restrict__ X,
                                                     const float* __restrict__ W,
                                                     const float* __restrict__ bias,
                                                     float* __restrict__ Y, int N) {
  __shared__ float Ws[64 * 128];
  __shared__ float Xs[32 * 128];
  int t = threadIdx.x;
  int rbase = blockIdx.x * 32;
  const float4* X4 = (const float4*)X;
  float4* Xs4 = (float4*)Xs;
#pragma unroll
  for (int i = 0; i < 4; i++) {
    int idx = t + 256 * i;          // float4 index in 32x128 tile
    int fr = idx >> 5, fc = idx & 31;
    int row = rbase + fr; if (row >= N) row = N - 1;
    Xs4[idx] = X4[(size_t)row * 32 + fc];
  }
  float acc[4][4];
#pragma unroll
  for (int r = 0; r < 4; r++)
#pragma unroll
    for (int cc = 0; cc < 4; cc++) acc[r][cc] = 0.f;
  int c0 = (t & 31) * 4;
  int rl = (t >> 5) * 4;
  const float4* W4 = (const float4*)W;
  float4* Ws4 = (float4*)Ws;
  for (int half = 0; half < 2; half++) {
    __syncthreads();
#pragma unroll
    for (int i = 0; i < 8; i++) {
      int idx = t + 256 * i;        // float4 index in 64x128 half
      Ws4[idx] = W4[half * 2048 + idx];
    }
    __syncthreads();
#pragma unroll 4
    for (int k = 0; k < 64; k++) {
      float4 w4 = *(const float4*)(Ws + k * 128 + c0);
      float xv[4];
#pragma unroll
      for (int r = 0; r < 4; r++) xv[r] = Xs[(rl + r) * 128 + half * 64 + k];
#pragma unroll
      for (int r = 0; r < 4; r++) {
        acc[r][0] = fmaf(xv[r], w4.x, acc[r][0]);
        acc[r][1] = fmaf(xv[r], w4.y, acc[r][1]);
        acc[r][2] = fmaf(xv[r], w4.z, acc[r][2]);
        acc[r][3] = fmaf(xv[r], w4.w, acc[r][3]);
      }
    }
  }
  float4 b4 = make_float4(0.f, 0.f, 0.f, 0.f);
  if (bias) b4 = *(const float4*)(bias + c0);
#pragma unroll
  for (int r = 0; r < 4; r++) {
    int row = rbase + rl + r;
    if (row < N) {
      float4 o;
      o.x = acc[r][0] + b4.x; o.y = acc[r][1] + b4.y;
      o.z = acc[r][2] + b4.z; o.w = acc[r][3] + b4.w;
      *(float4*)(Y + (size_t)row * 128 + c0) = o;
    }
  }
}

// ---------------- CSR aggregation: out[c] = relu?(dinv[c]*sum_e dinv[row]*ew*H[row] + b) ----
// One wave (64 lanes) per destination node; 2 features per lane. Metadata loaded 64 edges
// at a time (coalesced), broadcast via shfl; feature rows gathered as coalesced float2.
__global__ __launch_bounds__(256) void agg_kernel(const float* __restrict__ Hf,
                                                  float* __restrict__ out,
                                                  const int* __restrict__ starts,
                                                  const int* __restrict__ eidx,
                                                  const int* __restrict__ row,
                                                  const float* __restrict__ ew,
                                                  const float* __restrict__ dinv,
                                                  const float* __restrict__ bias,
                                                  int C, int relu) {
  int wid = (blockIdx.x * blockDim.x + threadIdx.x) >> 6;
  int lane = threadIdx.x & 63;
  if (wid >= C) return;
  int s = starts[wid], e = starts[wid + 1];
  float dc = dinv[wid];
  float ax = 0.f, ay = 0.f;
  for (int base = s; base < e; base += 64) {
    int n = e - base; if (n > 64) n = 64;
    int eoff = base + (lane < n ? lane : 0);
    int eid = eidx[eoff];
    int r = row[eid];
    float w = dinv[r] * (ew ? ew[eid] : 1.f);
    for (int j = 0; j < n; j++) {
      int rr = __shfl(r, j);
      float ww = __shfl(w, j);
      const float2 v = *(const float2*)(Hf + (size_t)rr * 128 + lane * 2);
      ax = fmaf(ww, v.x, ax);
      ay = fmaf(ww, v.y, ay);
    }
  }
  float ox = ax * dc + bias[lane * 2];
  float oy = ay * dc + bias[lane * 2 + 1];
  if (relu) { ox = fmaxf(ox, 0.f); oy = fmaxf(oy, 0.f); }
  *(float2*)(out + (size_t)wid * 128 + lane * 2) = make_float2(ox, oy);
}

// ---------------- seg_mean pooling: one wave per cluster ----------------
__global__ __launch_bounds__(256) void pool_kernel(const float* __restrict__ src,
                                                   float* __restrict__ out,
                                                   const int* __restrict__ starts,
                                                   const int* __restrict__ nidx, int C) {
  int wid = (blockIdx.x * blockDim.x + threadIdx.x) >> 6;
  int lane = threadIdx.x & 63;
  if (wid >= C) return;
  int s = starts[wid], e = starts[wid + 1];
  float ax = 0.f, ay = 0.f;
  for (int m = s; m < e; m++) {
    int id = nidx[m];
    const float2 v = *(const float2*)(src + (size_t)id * 128 + lane * 2);
    ax += v.x; ay += v.y;
  }
  float inv = (e > s) ? 1.f / (float)(e - s) : 0.f;
  *(float2*)(out + (size_t)wid * 128 + lane * 2) = make_float2(ax * inv, ay * inv);
}

// ---------------- out[i] = a[i] + b[cl[i]] (rowwise, float4) ----------------
__global__ void addgather_kernel(const float* __restrict__ a, const float* __restrict__ b,
                                 const int* __restrict__ cl, float* __restrict__ out, int nrows) {
  int g = blockIdx.x * 256 + threadIdx.x;  // float4 index
  if (g >= nrows * 32) return;
  int rowi = g >> 5;
  int c = cl[rowi];
  float4 va = ((const float4*)a)[g];
  float4 vb = ((const float4*)b)[(size_t)c * 32 + (g & 31)];
  float4 o;
  o.x = va.x + vb.x; o.y = va.y + vb.y; o.z = va.z + vb.z; o.w = va.w + vb.w;
  ((float4*)out)[g] = o;
}

// ---------------- host ----------------

extern "C" void kernel_launch(void* const* d_in, const int* in_sizes, int n_in,
                              void* d_out, int out_size, void* d_ws, size_t ws_size,
                              hipStream_t stream) {
  const float* x     = (const float*)d_in[0];
  const float* W_pre = (const float*)d_in[1];
  const float* b_pre = (const float*)d_in[2];
  const float* W_u0  = (const float*)d_in[3];
  const float* b_u0  = (const float*)d_in[4];
  const float* W_u1  = (const float*)d_in[5];
  const float* b_u1  = (const float*)d_in[6];
  const float* W_u2  = (const float*)d_in[7];
  const float* b_u2  = (const float*)d_in[8];
  const float* W_d0  = (const float*)d_in[9];
  const float* b_d0  = (const float*)d_in[10];
  const float* W_d1  = (const float*)d_in[11];
  const float* b_d1  = (const float*)d_in[12];
  const int* row0 = (const int*)d_in[13];
  const int* col0 = (const int*)d_in[14];
  const int* row1 = (const int*)d_in[16];
  const int* col1 = (const int*)d_in[17];
  const float* ew1 = (const float*)d_in[18];
  const int* row2 = (const int*)d_in[19];
  const int* col2 = (const int*)d_in[20];
  const float* ew2 = (const float*)d_in[21];
  const int* cluster1 = (const int*)d_in[22];
  const int* cluster2 = (const int*)d_in[23];
  int E0 = in_sizes[13], E1 = in_sizes[16], E2 = in_sizes[19];
  float* out = (float*)d_out;

  char* basep = (char*)d_ws;
  size_t off = 0;
  auto alloc = [&](size_t bytes) -> char* {
    char* p = basep + off;
    off = (off + bytes + 255) & ~(size_t)255;
    return p;
  };
  // zero-init region (one memset)
  int* counts0 = (int*)alloc((size_t)kN0 * 4);
  int* cursor0 = (int*)alloc((size_t)kN0 * 4);
  int* counts1 = (int*)alloc((size_t)kC1 * 4);
  int* cursor1 = (int*)alloc((size_t)kC1 * 4);
  int* counts2 = (int*)alloc((size_t)kC2 * 4);
  int* cursor2 = (int*)alloc((size_t)kC2 * 4);
  int* cntP1   = (int*)alloc((size_t)kC1 * 4);
  int* curP1   = (int*)alloc((size_t)kC1 * 4);
  int* cntP2   = (int*)alloc((size_t)kC2 * 4);
  int* curP2   = (int*)alloc((size_t)kC2 * 4);
  float* deg1w = (float*)alloc((size_t)kC1 * 4);
  float* deg2w = (float*)alloc((size_t)kC2 * 4);
  size_t zero_bytes = off;
  // non-zeroed
  int* starts0  = (int*)alloc((size_t)(kN0 + 1) * 4);
  int* starts1  = (int*)alloc((size_t)(kC1 + 1) * 4);
  int* starts2  = (int*)alloc((size_t)(kC2 + 1) * 4);
  int* startsP1 = (int*)alloc((size_t)(kC1 + 1) * 4);
  int* startsP2 = (int*)alloc((size_t)(kC2 + 1) * 4);
  int* eidx0 = (int*)alloc((size_t)E0 * 4);
  int* eidx1 = (int*)alloc((size_t)E1 * 4);
  int* eidx2 = (int*)alloc((size_t)E2 * 4);
  int* nidx1 = (int*)alloc((size_t)kN0 * 4);
  int* nidx2 = (int*)alloc((size_t)kC1 * 4);
  float* dinv0  = (float*)alloc((size_t)kN0 * 4);
  float* dinv1w = (float*)alloc((size_t)kC1 * 4);
  float* dinv1o = (float*)alloc((size_t)kC1 * 4);
  float* dinv2  = (float*)alloc((size_t)kC2 * 4);
  float* A   = (float*)alloc((size_t)kN0 * HH * 4);
  float* s1a = (float*)alloc((size_t)kC1 * HH * 4);
  float* s1b = (float*)alloc((size_t)kC1 * HH * 4);
  float* s1c = (float*)alloc((size_t)kC1 * HH * 4);
  float* s2a = (float*)alloc((size_t)kC2 * HH * 4);
  float* s2b = (float*)alloc((size_t)kC2 * HH * 4);

  hipMemsetAsync(d_ws, 0, zero_bytes, stream);

  auto cdiv = [](int a, int b) { return (a + b - 1) / b; };

  // CSR builds + degrees
  hist_kernel<<<cdiv(E0, 256), 256, 0, stream>>>(col0, E0, counts0);
  hist_kernel<<<cdiv(E1, 256), 256, 0, stream>>>(col1, E1, counts1);
  hist_kernel<<<cdiv(E2, 256), 256, 0, stream>>>(col2, E2, counts2);
  hist_kernel<<<cdiv(kN0, 256), 256, 0, stream>>>(cluster1, kN0, cntP1);
  hist_kernel<<<cdiv(kC1, 256), 256, 0, stream>>>(cluster2, kC1, cntP2);
  degw_kernel<<<cdiv(E1, 256), 256, 0, stream>>>(col1, ew1, E1, deg1w);
  degw_kernel<<<cdiv(E2, 256), 256, 0, stream>>>(col2, ew2, E2, deg2w);

  scan5_kernel<<<5, 1024, 0, stream>>>(counts0, starts0, kN0,
                                       counts1, starts1, kC1,
                                       counts2, starts2, kC2,
                                       cntP1, startsP1, kC1,
                                       cntP2, startsP2, kC2);

  scatter_kernel<<<cdiv(E0, 256), 256, 0, stream>>>(col0, E0, starts0, cursor0, eidx0);
  scatter_kernel<<<cdiv(E1, 256), 256, 0, stream>>>(col1, E1, starts1, cursor1, eidx1);
  scatter_kernel<<<cdiv(E2, 256), 256, 0, stream>>>(col2, E2, starts2, cursor2, eidx2);
  scatter_kernel<<<cdiv(kN0, 256), 256, 0, stream>>>(cluster1, kN0, startsP1, curP1, nidx1);
  scatter_kernel<<<cdiv(kC1, 256), 256, 0, stream>>>(cluster2, kC1, startsP2, curP2, nidx2);

  dinv_kernel<<<cdiv(kN0, 256), 256, 0, stream>>>(counts0, dinv0, counts1, dinv1o,
                                                  deg1w, dinv1w, deg2w, dinv2);

  // h = x@W_pre + b_pre -> A
  matmul_kernel<<<cdiv(kN0, 32), 256, 0, stream>>>(x, W_pre, b_pre, A, kN0);
  // t = h@W_u0 -> out (scratch)
  matmul_kernel<<<cdiv(kN0, 32), 256, 0, stream>>>(A, W_u0, nullptr, out, kN0);
  // x0 = relu(agg0(t) + b_u0) -> A      (ew0 is all-ones by construction)
  agg_kernel<<<cdiv(kN0, 4), 256, 0, stream>>>(out, A, starts0, eidx0, row0, nullptr,
                                               dinv0, b_u0, kN0, 1);
  // x1m = seg_mean(x0, cluster1) -> s1a
  pool_kernel<<<cdiv(kC1, 4), 256, 0, stream>>>(A, s1a, startsP1, nidx1, kC1);
  matmul_kernel<<<cdiv(kC1, 32), 256, 0, stream>>>(s1a, W_u1, nullptr, s1b, kC1);
  // x1 = relu(agg1_w(t1) + b_u1) -> s1a
  agg_kernel<<<cdiv(kC1, 4), 256, 0, stream>>>(s1b, s1a, starts1, eidx1, row1, ew1,
                                               dinv1w, b_u1, kC1, 1);
  // x2m = seg_mean(x1, cluster2) -> s2a
  pool_kernel<<<cdiv(kC2, 4), 256, 0, stream>>>(s1a, s2a, startsP2, nidx2, kC2);
  matmul_kernel<<<cdiv(kC2, 32), 256, 0, stream>>>(s2a, W_u2, nullptr, s2b, kC2);
  // x2 = relu(agg2_w(t2) + b_u2) -> s2a
  agg_kernel<<<cdiv(kC2, 4), 256, 0, stream>>>(s2b, s2a, starts2, eidx2, row2, ew2,
                                               dinv2, b_u2, kC2, 1);
  // y = x1 + x2[cluster2] -> s1b
  addgather_kernel<<<cdiv(kC1 * 32, 256), 256, 0, stream>>>(s1a, s2a, cluster2, s1b, kC1);
  matmul_kernel<<<cdiv(kC1, 32), 256, 0, stream>>>(s1b, W_d1, nullptr, s1c, kC1);
  // y1 = relu(agg1_ones(t) + b_d1) -> s1b
  agg_kernel<<<cdiv(kC1, 4), 256, 0, stream>>>(s1c, s1b, starts1, eidx1, row1, nullptr,
                                               dinv1o, b_d1, kC1, 1);
  // y0 = x0 + y1[cluster1] -> out (scratch)
  addgather_kernel<<<cdiv(kN0 * 32, 256), 256, 0, stream>>>(A, s1b, cluster1, out, kN0);
  matmul_kernel<<<cdiv(kN0, 32), 256, 0, stream>>>(out, W_d0, nullptr, A, kN0);
  // final: out = agg0(t) + b_d0 (no relu)
  agg_kernel<<<cdiv(kN0, 4), 256, 0, stream>>>(A, out, starts0, eidx0, row0, nullptr,
                                               dinv0, b_d0, kN0, 0);
}

// Round 2
// 1543.345 us; speedup vs baseline: 1.1446x; 1.1446x over previous
//
#include <hip/hip_runtime.h>

#define HH 128
static constexpr int kN0 = 100000;
static constexpr int kC1 = 10000;
static constexpr int kC2 = 1000;

// Contiguous segment layout for the 5 CSR histograms:
// [counts0 (kN0) | counts1 (kC1) | counts2 (kC2) | cntP1 (kC1) | cntP2 (kC2)]
static constexpr int B0 = kN0;              // 100000
static constexpr int B1 = B0 + kC1;         // 110000
static constexpr int B2 = B1 + kC2;         // 111000
static constexpr int B3 = B2 + kC1;         // 121000
static constexpr int NTOT = B3 + kC2;       // 122000
static constexpr int SCAN_NBLK = (NTOT + 1023) / 1024;  // 120

// ---------------- fused histogram (+ weighted degree) ----------------
__global__ void hist_fused_kernel(const int* __restrict__ col0, const int* __restrict__ col1,
                                  const int* __restrict__ col2, const int* __restrict__ cl1,
                                  const int* __restrict__ cl2, const float* __restrict__ ew1,
                                  const float* __restrict__ ew2, int E0, int E1, int E2,
                                  int* __restrict__ counts, float* __restrict__ deg1w,
                                  float* __restrict__ deg2w) {
  int g = blockIdx.x * 256 + threadIdx.x;
  int T0 = E0, T1 = T0 + E1, T2 = T1 + E2, T3 = T2 + kN0, T4 = T3 + kC1;
  if (g < T0) {
    atomicAdd(&counts[col0[g]], 1);
  } else if (g < T1) {
    int e = g - T0; int c = col1[e];
    atomicAdd(&counts[B0 + c], 1);
    atomicAdd(&deg1w[c], ew1[e]);
  } else if (g < T2) {
    int e = g - T1; int c = col2[e];
    atomicAdd(&counts[B1 + c], 1);
    atomicAdd(&deg2w[c], ew2[e]);
  } else if (g < T3) {
    atomicAdd(&counts[B2 + cl1[g - T2]], 1);
  } else if (g < T4) {
    atomicAdd(&counts[B3 + cl2[g - T3]], 1);
  }
}

// ---------------- 3-pass global exclusive scan over counts[NTOT] ----------------
__global__ __launch_bounds__(256) void scan_pass1(const int* __restrict__ cnt,
                                                  int* __restrict__ bsum) {
  int t = threadIdx.x;
  int base = blockIdx.x * 1024 + t * 4;
  int s = 0;
  if (base + 3 < NTOT) {
    int4 v = *(const int4*)(cnt + base);
    s = v.x + v.y + v.z + v.w;
  } else {
    for (int j = 0; j < 4; j++) if (base + j < NTOT) s += cnt[base + j];
  }
  for (int o = 32; o > 0; o >>= 1) s += __shfl_down(s, o);
  __shared__ int ws[4];
  if ((t & 63) == 0) ws[t >> 6] = s;
  __syncthreads();
  if (t == 0) bsum[blockIdx.x] = ws[0] + ws[1] + ws[2] + ws[3];
}

__global__ __launch_bounds__(128) void scan_pass2(const int* __restrict__ bsum,
                                                  int* __restrict__ boff,
                                                  int* __restrict__ startsg, int grand_total) {
  int t = threadIdx.x;
  int v = (t < SCAN_NBLK) ? bsum[t] : 0;
  int lane = t & 63;
  int incl = v;
  for (int o = 1; o < 64; o <<= 1) { int u = __shfl_up(incl, o); if (lane >= o) incl += u; }
  __shared__ int wtot[2];
  if (lane == 63) wtot[t >> 6] = incl;
  __syncthreads();
  int off = (t >= 64) ? wtot[0] : 0;
  if (t < SCAN_NBLK) boff[t] = off + incl - v;  // exclusive block offset
  if (t == 0) startsg[NTOT] = grand_total;      // sentinel for the last segment
}

__global__ __launch_bounds__(256) void scan_pass3(const int* __restrict__ cnt,
                                                  const int* __restrict__ boff,
                                                  int* __restrict__ startsg) {
  int t = threadIdx.x;
  int base = blockIdx.x * 1024 + t * 4;
  int4 v = make_int4(0, 0, 0, 0);
  if (base + 3 < NTOT) v = *(const int4*)(cnt + base);
  else { for (int j = 0; j < 4; j++) if (base + j < NTOT) ((int*)&v)[j] = cnt[base + j]; }
  int s = v.x + v.y + v.z + v.w;
  int lane = t & 63;
  int incl = s;
  for (int o = 1; o < 64; o <<= 1) { int u = __shfl_up(incl, o); if (lane >= o) incl += u; }
  __shared__ int wt[4];
  if (lane == 63) wt[t >> 6] = incl;
  __syncthreads();
  int woff = 0;
  for (int w = 0; w < (t >> 6); w++) woff += wt[w];
  int ex = boff[blockIdx.x] + woff + incl - s;
  if (base + 3 < NTOT) {
    int4 o4;
    o4.x = ex; o4.y = ex + v.x; o4.z = ex + v.x + v.y; o4.w = ex + v.x + v.y + v.z;
    *(int4*)(startsg + base) = o4;
  } else if (base < NTOT) {
    int p = ex;
    for (int j = 0; j < 4; j++) if (base + j < NTOT) { startsg[base + j] = p; p += ((int*)&v)[j]; }
  }
}

// ---------------- fused scatter ----------------
// idx_all layout mirrors the global scan: [eidx0 | eidx1 | eidx2 | nidx1 | nidx2]
__global__ void scatter_fused_kernel(const int* __restrict__ col0, const int* __restrict__ col1,
                                     const int* __restrict__ col2, const int* __restrict__ cl1,
                                     const int* __restrict__ cl2, int E0, int E1, int E2,
                                     const int* __restrict__ startsg, int* __restrict__ cursor,
                                     int* __restrict__ idx_all) {
  int g = blockIdx.x * 256 + threadIdx.x;
  int T0 = E0, T1 = T0 + E1, T2 = T1 + E2, T3 = T2 + kN0, T4 = T3 + kC1;
  int bin, val;
  if (g < T0) { bin = col0[g]; val = g; }
  else if (g < T1) { int e = g - T0; bin = B0 + col1[e]; val = e; }
  else if (g < T2) { int e = g - T1; bin = B1 + col2[e]; val = e; }
  else if (g < T3) { int e = g - T2; bin = B2 + cl1[e]; val = e; }
  else if (g < T4) { int e = g - T3; bin = B3 + cl2[e]; val = e; }
  else return;
  int p = atomicAdd(&cursor[bin], 1);
  idx_all[startsg[bin] + p] = val;
}

__global__ void dinv_kernel(const int* __restrict__ cnt0, float* __restrict__ d0,
                            const int* __restrict__ cnt1, float* __restrict__ d1o,
                            const float* __restrict__ deg1, float* __restrict__ d1w,
                            const float* __restrict__ deg2, float* __restrict__ d2) {
  int g = blockIdx.x * 256 + threadIdx.x;
  if (g < kN0) { int c = cnt0[g]; d0[g] = c > 0 ? rsqrtf((float)c) : 0.f; }
  if (g < kC1) {
    int c = cnt1[g]; d1o[g] = c > 0 ? rsqrtf((float)c) : 0.f;
    float w = deg1[g]; d1w[g] = w > 0.f ? rsqrtf(w) : 0.f;
  }
  if (g < kC2) { float w = deg2[g]; d2[g] = w > 0.f ? rsqrtf(w) : 0.f; }
}

// ---------------- GEMM: Y[N x 128] = X[N x 128] @ W[128 x 128] (+bias) ----------------
__global__ __launch_bounds__(256) void matmul_kernel(const float* __restrict__ X,
                                                     const float* __restrict__ W,
                                                     const float* __restrict__ bias,
                                                     float* __restrict__ Y, int N) {
  __shared__ float Ws[64 * 128];
  __shared__ float Xs[32 * 128];
  int t = threadIdx.x;
  int rbase = blockIdx.x * 32;
  const float4* X4 = (const float4*)X;
  float4* Xs4 = (float4*)Xs;
#pragma unroll
  for (int i = 0; i < 4; i++) {
    int idx = t + 256 * i;
    int fr = idx >> 5, fc = idx & 31;
    int row = rbase + fr; if (row >= N) row = N - 1;
    Xs4[idx] = X4[(size_t)row * 32 + fc];
  }
  float acc[4][4];
#pragma unroll
  for (int r = 0; r < 4; r++)
#pragma unroll
    for (int cc = 0; cc < 4; cc++) acc[r][cc] = 0.f;
  int c0 = (t & 31) * 4;
  int rl = (t >> 5) * 4;
  const float4* W4 = (const float4*)W;
  float4* Ws4 = (float4*)Ws;
  for (int half = 0; half < 2; half++) {
    __syncthreads();
#pragma unroll
    for (int i = 0; i < 8; i++) {
      int idx = t + 256 * i;
      Ws4[idx] = W4[half * 2048 + idx];
    }
    __syncthreads();
#pragma unroll 4
    for (int k = 0; k < 64; k++) {
      float4 w4 = *(const float4*)(Ws + k * 128 + c0);
      float xv[4];
#pragma unroll
      for (int r = 0; r < 4; r++) xv[r] = Xs[(rl + r) * 128 + half * 64 + k];
#pragma unroll
      for (int r = 0; r < 4; r++) {
        acc[r][0] = fmaf(xv[r], w4.x, acc[r][0]);
        acc[r][1] = fmaf(xv[r], w4.y, acc[r][1]);
        acc[r][2] = fmaf(xv[r], w4.z, acc[r][2]);
        acc[r][3] = fmaf(xv[r], w4.w, acc[r][3]);
      }
    }
  }
  float4 b4 = make_float4(0.f, 0.f, 0.f, 0.f);
  if (bias) b4 = *(const float4*)(bias + c0);
#pragma unroll
  for (int r = 0; r < 4; r++) {
    int row = rbase + rl + r;
    if (row < N) {
      float4 o;
      o.x = acc[r][0] + b4.x; o.y = acc[r][1] + b4.y;
      o.z = acc[r][2] + b4.z; o.w = acc[r][3] + b4.w;
      *(float4*)(Y + (size_t)row * 128 + c0) = o;
    }
  }
}

// ---------------- CSR aggregation ----------------
// One wave per destination node; 2 features per lane. starts carries GLOBAL positions
// into idx_all (segment base folded in); eidx values are segment-local edge ids.
__global__ __launch_bounds__(256) void agg_kernel(const float* __restrict__ Hf,
                                                  float* __restrict__ out,
                                                  const int* __restrict__ starts,
                                                  const int* __restrict__ eidx,
                                                  const int* __restrict__ row,
                                                  const float* __restrict__ ew,
                                                  const float* __restrict__ dinv,
                                                  const float* __restrict__ bias,
                                                  int C, int relu) {
  int wid = (blockIdx.x * blockDim.x + threadIdx.x) >> 6;
  int lane = threadIdx.x & 63;
  if (wid >= C) return;
  int s = starts[wid], e = starts[wid + 1];
  float dc = dinv[wid];
  float ax = 0.f, ay = 0.f;
  for (int base = s; base < e; base += 64) {
    int n = e - base; if (n > 64) n = 64;
    int eoff = base + (lane < n ? lane : 0);
    int eid = eidx[eoff];
    int r = row[eid];
    float w = dinv[r] * (ew ? ew[eid] : 1.f);
    for (int j = 0; j < n; j++) {
      int rr = __shfl(r, j);
      float ww = __shfl(w, j);
      const float2 v = *(const float2*)(Hf + (size_t)rr * 128 + lane * 2);
      ax = fmaf(ww, v.x, ax);
      ay = fmaf(ww, v.y, ay);
    }
  }
  float ox = ax * dc + bias[lane * 2];
  float oy = ay * dc + bias[lane * 2 + 1];
  if (relu) { ox = fmaxf(ox, 0.f); oy = fmaxf(oy, 0.f); }
  *(float2*)(out + (size_t)wid * 128 + lane * 2) = make_float2(ox, oy);
}

// ---------------- seg_mean pooling: one wave per cluster ----------------
__global__ __launch_bounds__(256) void pool_kernel(const float* __restrict__ src,
                                                   float* __restrict__ out,
                                                   const int* __restrict__ starts,
                                                   const int* __restrict__ nidx, int C) {
  int wid = (blockIdx.x * blockDim.x + threadIdx.x) >> 6;
  int lane = threadIdx.x & 63;
  if (wid >= C) return;
  int s = starts[wid], e = starts[wid + 1];
  float ax = 0.f, ay = 0.f;
  for (int m = s; m < e; m++) {
    int id = nidx[m];
    const float2 v = *(const float2*)(src + (size_t)id * 128 + lane * 2);
    ax += v.x; ay += v.y;
  }
  float inv = (e > s) ? 1.f / (float)(e - s) : 0.f;
  *(float2*)(out + (size_t)wid * 128 + lane * 2) = make_float2(ax * inv, ay * inv);
}

// ---------------- out[i] = a[i] + b[cl[i]] (rowwise, float4) ----------------
__global__ void addgather_kernel(const float* __restrict__ a, const float* __restrict__ b,
                                 const int* __restrict__ cl, float* __restrict__ out, int nrows) {
  int g = blockIdx.x * 256 + threadIdx.x;
  if (g >= nrows * 32) return;
  int rowi = g >> 5;
  int c = cl[rowi];
  float4 va = ((const float4*)a)[g];
  float4 vb = ((const float4*)b)[(size_t)c * 32 + (g & 31)];
  float4 o;
  o.x = va.x + vb.x; o.y = va.y + vb.y; o.z = va.z + vb.z; o.w = va.w + vb.w;
  ((float4*)out)[g] = o;
}

// ---------------- host ----------------

extern "C" void kernel_launch(void* const* d_in, const int* in_sizes, int n_in,
                              void* d_out, int out_size, void* d_ws, size_t ws_size,
                              hipStream_t stream) {
  const float* x     = (const float*)d_in[0];
  const float* W_pre = (const float*)d_in[1];
  const float* b_pre = (const float*)d_in[2];
  const float* W_u0  = (const float*)d_in[3];
  const float* b_u0  = (const float*)d_in[4];
  const float* W_u1  = (const float*)d_in[5];
  const float* b_u1  = (const float*)d_in[6];
  const float* W_u2  = (const float*)d_in[7];
  const float* b_u2  = (const float*)d_in[8];
  const float* W_d0  = (const float*)d_in[9];
  const float* b_d0  = (const float*)d_in[10];
  const float* W_d1  = (const float*)d_in[11];
  const float* b_d1  = (const float*)d_in[12];
  const int* row0 = (const int*)d_in[13];
  const int* col0 = (const int*)d_in[14];
  const int* row1 = (const int*)d_in[16];
  const int* col1 = (const int*)d_in[17];
  const float* ew1 = (const float*)d_in[18];
  const int* row2 = (const int*)d_in[19];
  const int* col2 = (const int*)d_in[20];
  const float* ew2 = (const float*)d_in[21];
  const int* cluster1 = (const int*)d_in[22];
  const int* cluster2 = (const int*)d_in[23];
  int E0 = in_sizes[13], E1 = in_sizes[16], E2 = in_sizes[19];
  float* out = (float*)d_out;

  char* basep = (char*)d_ws;
  size_t off = 0;
  auto alloc = [&](size_t bytes) -> char* {
    char* p = basep + off;
    off = (off + bytes + 255) & ~(size_t)255;
    return p;
  };
  // zero-init region (one memset)
  int* counts  = (int*)alloc((size_t)NTOT * 4);        // 5 histogram segments, contiguous
  int* cursor  = (int*)alloc((size_t)NTOT * 4);
  float* deg1w = (float*)alloc((size_t)kC1 * 4);
  float* deg2w = (float*)alloc((size_t)kC2 * 4);
  size_t zero_bytes = off;
  // non-zeroed
  int* startsg = (int*)alloc((size_t)(NTOT + 1) * 4);  // global exclusive scan
  int* bsum    = (int*)alloc(256 * 4);
  int* boff    = (int*)alloc(256 * 4);
  int idx_total = E0 + E1 + E2 + kN0 + kC1;
  int* idx_all = (int*)alloc((size_t)idx_total * 4);
  float* dinv0  = (float*)alloc((size_t)kN0 * 4);
  float* dinv1w = (float*)alloc((size_t)kC1 * 4);
  float* dinv1o = (float*)alloc((size_t)kC1 * 4);
  float* dinv2  = (float*)alloc((size_t)kC2 * 4);
  float* A   = (float*)alloc((size_t)kN0 * HH * 4);
  float* s1a = (float*)alloc((size_t)kC1 * HH * 4);
  float* s1b = (float*)alloc((size_t)kC1 * HH * 4);
  float* s1c = (float*)alloc((size_t)kC1 * HH * 4);
  float* s2a = (float*)alloc((size_t)kC2 * HH * 4);
  float* s2b = (float*)alloc((size_t)kC2 * HH * 4);

  hipMemsetAsync(d_ws, 0, zero_bytes, stream);

  auto cdiv = [](int a, int b) { return (a + b - 1) / b; };
  int Ttot = E0 + E1 + E2 + kN0 + kC1;

  hist_fused_kernel<<<cdiv(Ttot, 256), 256, 0, stream>>>(col0, col1, col2, cluster1, cluster2,
                                                         ew1, ew2, E0, E1, E2,
                                                         counts, deg1w, deg2w);
  scan_pass1<<<SCAN_NBLK, 256, 0, stream>>>(counts, bsum);
  scan_pass2<<<1, 128, 0, stream>>>(bsum, boff, startsg, Ttot);
  scan_pass3<<<SCAN_NBLK, 256, 0, stream>>>(counts, boff, startsg);
  scatter_fused_kernel<<<cdiv(Ttot, 256), 256, 0, stream>>>(col0, col1, col2, cluster1, cluster2,
                                                            E0, E1, E2, startsg, cursor, idx_all);
  dinv_kernel<<<cdiv(kN0, 256), 256, 0, stream>>>(counts, dinv0, counts + B0, dinv1o,
                                                  deg1w, dinv1w, deg2w, dinv2);

  // h = x@W_pre + b_pre -> A
  matmul_kernel<<<cdiv(kN0, 32), 256, 0, stream>>>(x, W_pre, b_pre, A, kN0);
  // t = h@W_u0 -> out (scratch)
  matmul_kernel<<<cdiv(kN0, 32), 256, 0, stream>>>(A, W_u0, nullptr, out, kN0);
  // x0 = relu(agg0(t) + b_u0) -> A      (ew0 all-ones)
  agg_kernel<<<cdiv(kN0, 4), 256, 0, stream>>>(out, A, startsg, idx_all, row0, nullptr,
                                               dinv0, b_u0, kN0, 1);
  // x1m = seg_mean(x0, cluster1) -> s1a
  pool_kernel<<<cdiv(kC1, 4), 256, 0, stream>>>(A, s1a, startsg + B2, idx_all, kC1);
  matmul_kernel<<<cdiv(kC1, 32), 256, 0, stream>>>(s1a, W_u1, nullptr, s1b, kC1);
  // x1 = relu(agg1_w(t1) + b_u1) -> s1a
  agg_kernel<<<cdiv(kC1, 4), 256, 0, stream>>>(s1b, s1a, startsg + B0, idx_all, row1, ew1,
                                               dinv1w, b_u1, kC1, 1);
  // x2m = seg_mean(x1, cluster2) -> s2a
  pool_kernel<<<cdiv(kC2, 4), 256, 0, stream>>>(s1a, s2a, startsg + B3, idx_all, kC2);
  matmul_kernel<<<cdiv(kC2, 32), 256, 0, stream>>>(s2a, W_u2, nullptr, s2b, kC2);
  // x2 = relu(agg2_w(t2) + b_u2) -> s2a
  agg_kernel<<<cdiv(kC2, 4), 256, 0, stream>>>(s2b, s2a, startsg + B1, idx_all, row2, ew2,
                                               dinv2, b_u2, kC2, 1);
  // y = x1 + x2[cluster2] -> s1b
  addgather_kernel<<<cdiv(kC1 * 32, 256), 256, 0, stream>>>(s1a, s2a, cluster2, s1b, kC1);
  matmul_kernel<<<cdiv(kC1, 32), 256, 0, stream>>>(s1b, W_d1, nullptr, s1c, kC1);
  // y1 = relu(agg1_ones(t) + b_d1) -> s1b
  agg_kernel<<<cdiv(kC1, 4), 256, 0, stream>>>(s1c, s1b, startsg + B0, idx_all, row1, nullptr,
                                               dinv1o, b_d1, kC1, 1);
  // y0 = x0 + y1[cluster1] -> out (scratch)
  addgather_kernel<<<cdiv(kN0 * 32, 256), 256, 0, stream>>>(A, s1b, cluster1, out, kN0);
  matmul_kernel<<<cdiv(kN0, 32), 256, 0, stream>>>(out, W_d0, nullptr, A, kN0);
  // final: out = agg0(t) + b_d0 (no relu)
  agg_kernel<<<cdiv(kN0, 4), 256, 0, stream>>>(A, out, startsg, idx_all, row0, nullptr,
                                               dinv0, b_d0, kN0, 0);
}

// Round 3
// 1282.645 us; speedup vs baseline: 1.3773x; 1.2033x over previous
//
#include <hip/hip_runtime.h>

#define HH 128
static constexpr int kN0 = 100000;
static constexpr int kC1 = 10000;
static constexpr int kC2 = 1000;

// Contiguous bin layout for the 5 CSR histograms:
// [bins0 (kN0) | bins1 (kC1) | bins2 (kC2) | binsP1 (kC1) | binsP2 (kC2)]
static constexpr int B0 = kN0;              // 100000
static constexpr int B1 = B0 + kC1;         // 110000
static constexpr int B2 = B1 + kC2;         // 111000
static constexpr int B3 = B2 + kC1;         // 121000
static constexpr int NTOT = B3 + kC2;       // 122000
static constexpr int SCAN_NBLK = (NTOT + 1023) / 1024;  // 120

// ---------------- fused histogram + position (the atomic IS the cursor) ----------------
// One bin per 64B line (stride 16 ints) to kill line-level atomic contention.
__global__ void hist_pos_kernel(const int* __restrict__ col0, const int* __restrict__ col1,
                                const int* __restrict__ col2, const int* __restrict__ cl1,
                                const int* __restrict__ cl2, int E0, int E1, int E2,
                                int* __restrict__ scnt, int* __restrict__ pos) {
  int g = blockIdx.x * 256 + threadIdx.x;
  int T0 = E0, T1 = T0 + E1, T2 = T1 + E2, T3 = T2 + kN0, T4 = T3 + kC1;
  int bin;
  if (g < T0)      bin = col0[g];
  else if (g < T1) bin = B0 + col1[g - T0];
  else if (g < T2) bin = B1 + col2[g - T1];
  else if (g < T3) bin = B2 + cl1[g - T2];
  else if (g < T4) bin = B3 + cl2[g - T3];
  else return;
  int p = atomicAdd(&scnt[(size_t)bin * 16], 1);
  pos[g] = p;
}

// strided -> packed counts (scan input)
__global__ void compact_kernel(const int* __restrict__ scnt, int* __restrict__ packed) {
  int g = blockIdx.x * 256 + threadIdx.x;
  if (g < NTOT) packed[g] = scnt[(size_t)g * 16];
}

// ---------------- 3-pass global exclusive scan over packed[NTOT] ----------------
__global__ __launch_bounds__(256) void scan_pass1(const int* __restrict__ cnt,
                                                  int* __restrict__ bsum) {
  int t = threadIdx.x;
  int base = blockIdx.x * 1024 + t * 4;
  int s = 0;
  if (base + 3 < NTOT) {
    int4 v = *(const int4*)(cnt + base);
    s = v.x + v.y + v.z + v.w;
  } else {
    for (int j = 0; j < 4; j++) if (base + j < NTOT) s += cnt[base + j];
  }
  for (int o = 32; o > 0; o >>= 1) s += __shfl_down(s, o);
  __shared__ int ws[4];
  if ((t & 63) == 0) ws[t >> 6] = s;
  __syncthreads();
  if (t == 0) bsum[blockIdx.x] = ws[0] + ws[1] + ws[2] + ws[3];
}

__global__ __launch_bounds__(128) void scan_pass2(const int* __restrict__ bsum,
                                                  int* __restrict__ boff,
                                                  int* __restrict__ startsg, int grand_total) {
  int t = threadIdx.x;
  int v = (t < SCAN_NBLK) ? bsum[t] : 0;
  int lane = t & 63;
  int incl = v;
  for (int o = 1; o < 64; o <<= 1) { int u = __shfl_up(incl, o); if (lane >= o) incl += u; }
  __shared__ int wtot[2];
  if (lane == 63) wtot[t >> 6] = incl;
  __syncthreads();
  int off = (t >= 64) ? wtot[0] : 0;
  if (t < SCAN_NBLK) boff[t] = off + incl - v;  // exclusive block offset
  if (t == 0) startsg[NTOT] = grand_total;      // sentinel
}

__global__ __launch_bounds__(256) void scan_pass3(const int* __restrict__ cnt,
                                                  const int* __restrict__ boff,
                                                  int* __restrict__ startsg) {
  int t = threadIdx.x;
  int base = blockIdx.x * 1024 + t * 4;
  int4 v = make_int4(0, 0, 0, 0);
  if (base + 3 < NTOT) v = *(const int4*)(cnt + base);
  else { for (int j = 0; j < 4; j++) if (base + j < NTOT) ((int*)&v)[j] = cnt[base + j]; }
  int s = v.x + v.y + v.z + v.w;
  int lane = t & 63;
  int incl = s;
  for (int o = 1; o < 64; o <<= 1) { int u = __shfl_up(incl, o); if (lane >= o) incl += u; }
  __shared__ int wt[4];
  if (lane == 63) wt[t >> 6] = incl;
  __syncthreads();
  int woff = 0;
  for (int w = 0; w < (t >> 6); w++) woff += wt[w];
  int ex = boff[blockIdx.x] + woff + incl - s;
  if (base + 3 < NTOT) {
    int4 o4;
    o4.x = ex; o4.y = ex + v.x; o4.z = ex + v.x + v.y; o4.w = ex + v.x + v.y + v.z;
    *(int4*)(startsg + base) = o4;
  } else if (base < NTOT) {
    int p = ex;
    for (int j = 0; j < 4; j++) if (base + j < NTOT) { startsg[base + j] = p; p += ((int*)&v)[j]; }
  }
}

// ---------------- atomic-free placement: permute row/ew into CSR order ----------------
// rowS[dst]: source node for edge segments, member node id for pool segments.
// ewS (offset by -E0 at call site) only written for seg1/seg2.
__global__ void place_kernel(const int* __restrict__ col0, const int* __restrict__ col1,
                             const int* __restrict__ col2, const int* __restrict__ cl1,
                             const int* __restrict__ cl2, const int* __restrict__ row0,
                             const int* __restrict__ row1, const int* __restrict__ row2,
                             const float* __restrict__ ew1, const float* __restrict__ ew2,
                             int E0, int E1, int E2, const int* __restrict__ startsg,
                             const int* __restrict__ pos, int* __restrict__ rowS,
                             float* __restrict__ ewSm) {  // ewSm == ewS - E0
  int g = blockIdx.x * 256 + threadIdx.x;
  int T0 = E0, T1 = T0 + E1, T2 = T1 + E2, T3 = T2 + kN0, T4 = T3 + kC1;
  int bin, src; float w = 0.f; bool has_w = false;
  if (g < T0) { bin = col0[g]; src = row0[g]; }
  else if (g < T1) { int e = g - T0; bin = B0 + col1[e]; src = row1[e]; w = ew1[e]; has_w = true; }
  else if (g < T2) { int e = g - T1; bin = B1 + col2[e]; src = row2[e]; w = ew2[e]; has_w = true; }
  else if (g < T3) { int e = g - T2; bin = B2 + cl1[e]; src = e; }
  else if (g < T4) { int e = g - T3; bin = B3 + cl2[e]; src = e; }
  else return;
  int dst = startsg[bin] + pos[g];
  rowS[dst] = src;
  if (has_w) ewSm[dst] = w;
}

// ---------------- dinv + weighted degrees (CSR segment sums, coalesced) ----------------
__global__ void dinv_kernel(const int* __restrict__ startsg, const float* __restrict__ ewSm,
                            float* __restrict__ d0, float* __restrict__ d1w,
                            float* __restrict__ d1o, float* __restrict__ d2) {
  int t = blockIdx.x * 256 + threadIdx.x;
  if (t < kN0) {
    int c = startsg[t + 1] - startsg[t];
    d0[t] = c > 0 ? rsqrtf((float)c) : 0.f;
  }
  int wid = t >> 6, lane = t & 63;
  if (wid < kC1) {
    int s = startsg[B0 + wid], e = startsg[B0 + wid + 1];
    float a = 0.f;
    for (int k = s + lane; k < e; k += 64) a += ewSm[k];
    for (int o = 32; o > 0; o >>= 1) a += __shfl_down(a, o);
    if (lane == 0) {
      d1w[wid] = a > 0.f ? rsqrtf(a) : 0.f;
      int c = e - s;
      d1o[wid] = c > 0 ? rsqrtf((float)c) : 0.f;
    }
  } else if (wid < kC1 + kC2) {
    int w2 = wid - kC1;
    int s = startsg[B1 + w2], e = startsg[B1 + w2 + 1];
    float a = 0.f;
    for (int k = s + lane; k < e; k += 64) a += ewSm[k];
    for (int o = 32; o > 0; o >>= 1) a += __shfl_down(a, o);
    if (lane == 0) d2[w2] = a > 0.f ? rsqrtf(a) : 0.f;
  }
}

// ---------------- GEMM: Y[N x 128] = X[N x 128] @ W[128 x 128] (+bias) ----------------
__global__ __launch_bounds__(256) void matmul_kernel(const float* __restrict__ X,
                                                     const float* __restrict__ W,
                                                     const float* __restrict__ bias,
                                                     float* __restrict__ Y, int N) {
  __shared__ float Ws[64 * 128];
  __shared__ float Xs[32 * 128];
  int t = threadIdx.x;
  int rbase = blockIdx.x * 32;
  const float4* X4 = (const float4*)X;
  float4* Xs4 = (float4*)Xs;
#pragma unroll
  for (int i = 0; i < 4; i++) {
    int idx = t + 256 * i;
    int fr = idx >> 5, fc = idx & 31;
    int row = rbase + fr; if (row >= N) row = N - 1;
    Xs4[idx] = X4[(size_t)row * 32 + fc];
  }
  float acc[4][4];
#pragma unroll
  for (int r = 0; r < 4; r++)
#pragma unroll
    for (int cc = 0; cc < 4; cc++) acc[r][cc] = 0.f;
  int c0 = (t & 31) * 4;
  int rl = (t >> 5) * 4;
  const float4* W4 = (const float4*)W;
  float4* Ws4 = (float4*)Ws;
  for (int half = 0; half < 2; half++) {
    __syncthreads();
#pragma unroll
    for (int i = 0; i < 8; i++) {
      int idx = t + 256 * i;
      Ws4[idx] = W4[half * 2048 + idx];
    }
    __syncthreads();
#pragma unroll 4
    for (int k = 0; k < 64; k++) {
      float4 w4 = *(const float4*)(Ws + k * 128 + c0);
      float xv[4];
#pragma unroll
      for (int r = 0; r < 4; r++) xv[r] = Xs[(rl + r) * 128 + half * 64 + k];
#pragma unroll
      for (int r = 0; r < 4; r++) {
        acc[r][0] = fmaf(xv[r], w4.x, acc[r][0]);
        acc[r][1] = fmaf(xv[r], w4.y, acc[r][1]);
        acc[r][2] = fmaf(xv[r], w4.z, acc[r][2]);
        acc[r][3] = fmaf(xv[r], w4.w, acc[r][3]);
      }
    }
  }
  float4 b4 = make_float4(0.f, 0.f, 0.f, 0.f);
  if (bias) b4 = *(const float4*)(bias + c0);
#pragma unroll
  for (int r = 0; r < 4; r++) {
    int row = rbase + rl + r;
    if (row < N) {
      float4 o;
      o.x = acc[r][0] + b4.x; o.y = acc[r][1] + b4.y;
      o.z = acc[r][2] + b4.z; o.w = acc[r][3] + b4.w;
      *(float4*)(Y + (size_t)row * 128 + c0) = o;
    }
  }
}

// ---------------- CSR aggregation ----------------
// One wave per destination node; 2 features per lane. Metadata (rowS, ewS) is already
// permuted into CSR order -> fully coalesced loads, no indirection.
__global__ __launch_bounds__(256) void agg_kernel(const float* __restrict__ Hf,
                                                  float* __restrict__ out,
                                                  const int* __restrict__ starts,
                                                  const int* __restrict__ rowS,
                                                  const float* __restrict__ ewSm,
                                                  const float* __restrict__ dinv,
                                                  const float* __restrict__ bias,
                                                  int C, int relu) {
  int wid = (blockIdx.x * blockDim.x + threadIdx.x) >> 6;
  int lane = threadIdx.x & 63;
  if (wid >= C) return;
  int s = starts[wid], e = starts[wid + 1];
  float dc = dinv[wid];
  float ax = 0.f, ay = 0.f;
  for (int base = s; base < e; base += 64) {
    int n = e - base; if (n > 64) n = 64;
    int moff = base + (lane < n ? lane : 0);
    int r = rowS[moff];
    float w = dinv[r] * (ewSm ? ewSm[moff] : 1.f);
    for (int j = 0; j < n; j++) {
      int rr = __shfl(r, j);
      float ww = __shfl(w, j);
      const float2 v = *(const float2*)(Hf + (size_t)rr * 128 + lane * 2);
      ax = fmaf(ww, v.x, ax);
      ay = fmaf(ww, v.y, ay);
    }
  }
  float ox = ax * dc + bias[lane * 2];
  float oy = ay * dc + bias[lane * 2 + 1];
  if (relu) { ox = fmaxf(ox, 0.f); oy = fmaxf(oy, 0.f); }
  *(float2*)(out + (size_t)wid * 128 + lane * 2) = make_float2(ox, oy);
}

// ---------------- seg_mean pooling: one wave per cluster ----------------
__global__ __launch_bounds__(256) void pool_kernel(const float* __restrict__ src,
                                                   float* __restrict__ out,
                                                   const int* __restrict__ starts,
                                                   const int* __restrict__ rowS, int C) {
  int wid = (blockIdx.x * blockDim.x + threadIdx.x) >> 6;
  int lane = threadIdx.x & 63;
  if (wid >= C) return;
  int s = starts[wid], e = starts[wid + 1];
  float ax = 0.f, ay = 0.f;
  for (int m = s; m < e; m++) {
    int id = rowS[m];
    const float2 v = *(const float2*)(src + (size_t)id * 128 + lane * 2);
    ax += v.x; ay += v.y;
  }
  float inv = (e > s) ? 1.f / (float)(e - s) : 0.f;
  *(float2*)(out + (size_t)wid * 128 + lane * 2) = make_float2(ax * inv, ay * inv);
}

// ---------------- out[i] = a[i] + b[cl[i]] (rowwise, float4) ----------------
__global__ void addgather_kernel(const float* __restrict__ a, const float* __restrict__ b,
                                 const int* __restrict__ cl, float* __restrict__ out, int nrows) {
  int g = blockIdx.x * 256 + threadIdx.x;
  if (g >= nrows * 32) return;
  int rowi = g >> 5;
  int c = cl[rowi];
  float4 va = ((const float4*)a)[g];
  float4 vb = ((const float4*)b)[(size_t)c * 32 + (g & 31)];
  float4 o;
  o.x = va.x + vb.x; o.y = va.y + vb.y; o.z = va.z + vb.z; o.w = va.w + vb.w;
  ((float4*)out)[g] = o;
}

// ---------------- host ----------------

extern "C" void kernel_launch(void* const* d_in, const int* in_sizes, int n_in,
                              void* d_out, int out_size, void* d_ws, size_t ws_size,
                              hipStream_t stream) {
  const float* x     = (const float*)d_in[0];
  const float* W_pre = (const float*)d_in[1];
  const float* b_pre = (const float*)d_in[2];
  const float* W_u0  = (const float*)d_in[3];
  const float* b_u0  = (const float*)d_in[4];
  const float* W_u1  = (const float*)d_in[5];
  const float* b_u1  = (const float*)d_in[6];
  const float* W_u2  = (const float*)d_in[7];
  const float* b_u2  = (const float*)d_in[8];
  const float* W_d0  = (const float*)d_in[9];
  const float* b_d0  = (const float*)d_in[10];
  const float* W_d1  = (const float*)d_in[11];
  const float* b_d1  = (const float*)d_in[12];
  const int* row0 = (const int*)d_in[13];
  const int* col0 = (const int*)d_in[14];
  const int* row1 = (const int*)d_in[16];
  const int* col1 = (const int*)d_in[17];
  const float* ew1 = (const float*)d_in[18];
  const int* row2 = (const int*)d_in[19];
  const int* col2 = (const int*)d_in[20];
  const float* ew2 = (const float*)d_in[21];
  const int* cluster1 = (const int*)d_in[22];
  const int* cluster2 = (const int*)d_in[23];
  int E0 = in_sizes[13], E1 = in_sizes[16], E2 = in_sizes[19];
  float* out = (float*)d_out;

  char* basep = (char*)d_ws;
  size_t off = 0;
  auto alloc = [&](size_t bytes) -> char* {
    char* p = basep + off;
    off = (off + bytes + 255) & ~(size_t)255;
    return p;
  };
  // zero-init region (one memset): strided counters, one bin per 64B line
  int* scnt = (int*)alloc((size_t)NTOT * 16 * 4);
  size_t zero_bytes = off;
  // non-zeroed
  int* packed  = (int*)alloc((size_t)NTOT * 4);
  int* startsg = (int*)alloc((size_t)(NTOT + 1) * 4);
  int* bsum    = (int*)alloc(256 * 4);
  int* boff    = (int*)alloc(256 * 4);
  int Ttot = E0 + E1 + E2 + kN0 + kC1;
  int* pos   = (int*)alloc((size_t)Ttot * 4);
  int* rowS  = (int*)alloc((size_t)Ttot * 4);
  float* ewS = (float*)alloc((size_t)(E1 + E2) * 4);
  float* ewSm = ewS - E0;  // indexed by global CSR position (seg1/seg2 region only)
  float* dinv0  = (float*)alloc((size_t)kN0 * 4);
  float* dinv1w = (float*)alloc((size_t)kC1 * 4);
  float* dinv1o = (float*)alloc((size_t)kC1 * 4);
  float* dinv2  = (float*)alloc((size_t)kC2 * 4);
  float* A   = (float*)alloc((size_t)kN0 * HH * 4);
  float* s1a = (float*)alloc((size_t)kC1 * HH * 4);
  float* s1b = (float*)alloc((size_t)kC1 * HH * 4);
  float* s1c = (float*)alloc((size_t)kC1 * HH * 4);
  float* s2a = (float*)alloc((size_t)kC2 * HH * 4);
  float* s2b = (float*)alloc((size_t)kC2 * HH * 4);

  hipMemsetAsync(d_ws, 0, zero_bytes, stream);

  auto cdiv = [](int a, int b) { return (a + b - 1) / b; };

  hist_pos_kernel<<<cdiv(Ttot, 256), 256, 0, stream>>>(col0, col1, col2, cluster1, cluster2,
                                                       E0, E1, E2, scnt, pos);
  compact_kernel<<<cdiv(NTOT, 256), 256, 0, stream>>>(scnt, packed);
  scan_pass1<<<SCAN_NBLK, 256, 0, stream>>>(packed, bsum);
  scan_pass2<<<1, 128, 0, stream>>>(bsum, boff, startsg, Ttot);
  scan_pass3<<<SCAN_NBLK, 256, 0, stream>>>(packed, boff, startsg);
  place_kernel<<<cdiv(Ttot, 256), 256, 0, stream>>>(col0, col1, col2, cluster1, cluster2,
                                                    row0, row1, row2, ew1, ew2, E0, E1, E2,
                                                    startsg, pos, rowS, ewSm);
  dinv_kernel<<<cdiv((kC1 + kC2) * 64, 256), 256, 0, stream>>>(startsg, ewSm, dinv0, dinv1w,
                                                               dinv1o, dinv2);

  // h = x@W_pre + b_pre -> A
  matmul_kernel<<<cdiv(kN0, 32), 256, 0, stream>>>(x, W_pre, b_pre, A, kN0);
  // t = h@W_u0 -> out (scratch)
  matmul_kernel<<<cdiv(kN0, 32), 256, 0, stream>>>(A, W_u0, nullptr, out, kN0);
  // x0 = relu(agg0(t) + b_u0) -> A      (ew0 all-ones)
  agg_kernel<<<cdiv(kN0, 4), 256, 0, stream>>>(out, A, startsg, rowS, nullptr,
                                               dinv0, b_u0, kN0, 1);
  // x1m = seg_mean(x0, cluster1) -> s1a
  pool_kernel<<<cdiv(kC1, 4), 256, 0, stream>>>(A, s1a, startsg + B2, rowS, kC1);
  matmul_kernel<<<cdiv(kC1, 32), 256, 0, stream>>>(s1a, W_u1, nullptr, s1b, kC1);
  // x1 = relu(agg1_w(t1) + b_u1) -> s1a
  agg_kernel<<<cdiv(kC1, 4), 256, 0, stream>>>(s1b, s1a, startsg + B0, rowS, ewSm,
                                               dinv1w, b_u1, kC1, 1);
  // x2m = seg_mean(x1, cluster2) -> s2a
  pool_kernel<<<cdiv(kC2, 4), 256, 0, stream>>>(s1a, s2a, startsg + B3, rowS, kC2);
  matmul_kernel<<<cdiv(kC2, 32), 256, 0, stream>>>(s2a, W_u2, nullptr, s2b, kC2);
  // x2 = relu(agg2_w(t2) + b_u2) -> s2a
  agg_kernel<<<cdiv(kC2, 4), 256, 0, stream>>>(s2b, s2a, startsg + B1, rowS, ewSm,
                                               dinv2, b_u2, kC2, 1);
  // y = x1 + x2[cluster2] -> s1b
  addgather_kernel<<<cdiv(kC1 * 32, 256), 256, 0, stream>>>(s1a, s2a, cluster2, s1b, kC1);
  matmul_kernel<<<cdiv(kC1, 32), 256, 0, stream>>>(s1b, W_d1, nullptr, s1c, kC1);
  // y1 = relu(agg1_ones(t) + b_d1) -> s1b
  agg_kernel<<<cdiv(kC1, 4), 256, 0, stream>>>(s1c, s1b, startsg + B0, rowS, nullptr,
                                               dinv1o, b_d1, kC1, 1);
  // y0 = x0 + y1[cluster1] -> out (scratch)
  addgather_kernel<<<cdiv(kN0 * 32, 256), 256, 0, stream>>>(A, s1b, cluster1, out, kN0);
  matmul_kernel<<<cdiv(kN0, 32), 256, 0, stream>>>(out, W_d0, nullptr, A, kN0);
  // final: out = agg0(t) + b_d0 (no relu)
  agg_kernel<<<cdiv(kN0, 4), 256, 0, stream>>>(A, out, startsg, rowS, nullptr,
                                               dinv0, b_d0, kN0, 0);
}